// Round 1
// baseline (111.214 us; speedup 1.0000x reference)
//
#include <hip/hip_runtime.h>
#include <hip/hip_bf16.h>

#define B_      4
#define L_      2048
#define NE_     768
#define NOUT_   256     // N_BINS * N_HIDDEN
#define NH_     32
#define NB_     8
#define V_      64
#define VOCAB_  1270
#define NC_     32          // chunks per batch row
#define CS_     (L_ / NC_)  // 64
#define BM_     16
#define KT_     32
#define NROWS_  (B_ * L_)   // 8192
#define GRID_MAIN_ (NROWS_ / BM_)  // 512
#define INV_M_  (1.0f / 4194304.0f)  // 1/(B*L*NB*V)

// ---------------- workspace layout (bytes) ----------------
// [0      , 5120  ) tmap      int[1280]
// [8192   , 40960 ) mt        int[B*L]
// [40960  , 73728 ) firstocc  int[B*NC*V]
// [73728  , 2170880) tte      float[B*L*V]
// [2170880, 2172928) partials float[512]

__global__ void k_tmap(const int* __restrict__ task_tokens, int* __restrict__ tmap) {
    for (int t = threadIdx.x; t < VOCAB_; t += blockDim.x) tmap[t] = 0;
    __syncthreads();
    if (threadIdx.x < V_) tmap[task_tokens[threadIdx.x]] = threadIdx.x + 1;
}

__global__ void k_mt(const int* __restrict__ targets, const int* __restrict__ tmap,
                     int* __restrict__ mt) {
    int idx = blockIdx.x * blockDim.x + threadIdx.x;
    if (idx < B_ * L_) mt[idx] = tmap[targets[idx]] - 1;   // -1 = not a task token
}

// per-chunk first occurrence of class v (lane = v)
__global__ void k_firstocc(const int* __restrict__ mt, int* __restrict__ firstocc) {
    __shared__ int s[CS_];
    int b = blockIdx.x / NC_, c = blockIdx.x % NC_;
    int v = threadIdx.x;
    s[v] = mt[b * L_ + c * CS_ + v];
    __syncthreads();
    int first = 0x7FFFFFFF;
    for (int j = CS_ - 1; j >= 0; --j)
        if (s[j] == v) first = c * CS_ + j;
    firstocc[(b * NC_ + c) * V_ + v] = first;
}

// suffix-min across later chunks + backward scan within chunk; emit tte directly.
// tte[b,i,v] = targets_age[b, tok] - age[b,i] if event exists, else -1.0f sentinel.
__global__ void k_tte(const int* __restrict__ mt, const int* __restrict__ firstocc,
                      const float* __restrict__ age, const float* __restrict__ targets_age,
                      float* __restrict__ tte) {
    __shared__ int s[CS_];
    __shared__ float sage[CS_];
    int b = blockIdx.x / NC_, c = blockIdx.x % NC_;
    int v = threadIdx.x;
    s[v] = mt[b * L_ + c * CS_ + v];
    sage[v] = age[b * L_ + c * CS_ + v];
    __syncthreads();
    int cur = 0x7FFFFFFF;
    for (int cc = c + 1; cc < NC_; ++cc)
        cur = min(cur, firstocc[(b * NC_ + cc) * V_ + v]);
    for (int j = CS_ - 1; j >= 0; --j) {
        int i = c * CS_ + j;
        if (s[j] == v) cur = i;               // event at i itself counts (k >= i)
        float val = -1.0f;
        if (cur != 0x7FFFFFFF) val = targets_age[b * L_ + cur] - sage[j];
        tte[(b * L_ + i) * V_ + v] = val;
    }
}

// main: fp32 GEMM1 (BM=16 rows x 256 cols) + fused head, one partial per block
__global__ void __launch_bounds__(256)
k_main(const float* __restrict__ h, const float* __restrict__ age,
       const float* __restrict__ targets_age,
       const float* __restrict__ W1, const float* __restrict__ W2,
       const float* __restrict__ time_bins,
       const float* __restrict__ tte, float* __restrict__ partials) {
    __shared__ float A_lds[BM_][KT_];
    __shared__ float Bt_lds[KT_][NOUT_];
    __shared__ float hh_lds[BM_][NOUT_];
    __shared__ float red_lds[4];

    const int tid = threadIdx.x;
    const int tx = tid & 63;        // col group (4 cols each)
    const int ty = tid >> 6;        // wave index = row group (4 rows each)
    const int r0 = blockIdx.x * BM_;

    float acc[4][4] = {};

    for (int kt = 0; kt < NE_; kt += KT_) {
        // stage A tile: 16 x 32 floats
        #pragma unroll
        for (int q = 0; q < 2; ++q) {
            int ee = tid + q * 256;
            int row = ee >> 5, k = ee & 31;
            A_lds[row][k] = h[(r0 + row) * NE_ + kt + k];
        }
        // stage B tile: 32 x 256 floats (float4 coalesced)
        #pragma unroll
        for (int q = 0; q < 8; ++q) {
            int e4 = tid + q * 256;
            int k = e4 >> 6, c4 = (e4 & 63) << 2;
            float4 bv = *reinterpret_cast<const float4*>(&W1[(kt + k) * NOUT_ + c4]);
            *reinterpret_cast<float4*>(&Bt_lds[k][c4]) = bv;
        }
        __syncthreads();
        #pragma unroll
        for (int k = 0; k < KT_; ++k) {
            float a0 = A_lds[ty * 4 + 0][k];
            float a1 = A_lds[ty * 4 + 1][k];
            float a2 = A_lds[ty * 4 + 2][k];
            float a3 = A_lds[ty * 4 + 3][k];
            float4 bv = *reinterpret_cast<const float4*>(&Bt_lds[k][tx * 4]);
            acc[0][0] += a0 * bv.x; acc[0][1] += a0 * bv.y; acc[0][2] += a0 * bv.z; acc[0][3] += a0 * bv.w;
            acc[1][0] += a1 * bv.x; acc[1][1] += a1 * bv.y; acc[1][2] += a1 * bv.z; acc[1][3] += a1 * bv.w;
            acc[2][0] += a2 * bv.x; acc[2][1] += a2 * bv.y; acc[2][2] += a2 * bv.z; acc[2][3] += a2 * bv.w;
            acc[3][0] += a3 * bv.x; acc[3][1] += a3 * bv.y; acc[3][2] += a3 * bv.z; acc[3][3] += a3 * bv.w;
        }
        __syncthreads();
    }

    // stash hh tile
    #pragma unroll
    for (int rr = 0; rr < 4; ++rr)
        #pragma unroll
        for (int cc = 0; cc < 4; ++cc)
            hh_lds[ty * 4 + rr][tx * 4 + cc] = acc[rr][cc];
    __syncthreads();

    // ---- phase 2: per-row head; lane v = tx ----
    const int v = tx;
    float w2reg[NH_];
    #pragma unroll
    for (int j = 0; j < NH_; ++j) w2reg[j] = W2[j * V_ + v];
    float tb[NB_ + 1];
    #pragma unroll
    for (int n = 0; n <= NB_; ++n) tb[n] = time_bins[n];

    float lane_total = 0.0f;
    for (int rr = 0; rr < 4; ++rr) {
        int rl = ty * 4 + rr;
        int r = r0 + rl;
        int b = r >> 11;              // / L_
        float ll[NB_];
        #pragma unroll
        for (int n = 0; n < NB_; ++n) {
            float s = 0.0f;
            #pragma unroll
            for (int j4 = 0; j4 < 8; ++j4) {
                float4 hv = *reinterpret_cast<const float4*>(&hh_lds[rl][n * NH_ + j4 * 4]);
                s += hv.x * w2reg[j4 * 4 + 0] + hv.y * w2reg[j4 * 4 + 1]
                   + hv.z * w2reg[j4 * 4 + 2] + hv.w * w2reg[j4 * 4 + 3];
            }
            ll[n] = s;
        }
        float ex[NB_];
        #pragma unroll
        for (int n = 0; n < NB_; ++n) ex[n] = __expf(ll[n]);

        float lc = targets_age[b * L_ + (L_ - 1)] - age[r];
        float part = 0.0f;
        float cn[NB_];
        #pragma unroll
        for (int n = 0; n < NB_; ++n) {
            float w = tb[n + 1] - tb[n];
            cn[n] = fminf(fmaxf(lc, 0.0f), w);
            part += cn[n] * ex[n];
        }
        float t = tte[r * V_ + v];
        #pragma unroll
        for (int n = 0; n < NB_; ++n) {
            bool occ = (t > tb[n]) && (t <= tb[n + 1]);
            if (occ) part += ex[n] * (t - cn[n]) - ll[n];
        }
        lane_total += part;
    }

    // block reduction -> one partial per block (deterministic)
    #pragma unroll
    for (int off = 32; off > 0; off >>= 1)
        lane_total += __shfl_xor(lane_total, off);
    if (tx == 0) red_lds[ty] = lane_total;
    __syncthreads();
    if (tid == 0)
        partials[blockIdx.x] = red_lds[0] + red_lds[1] + red_lds[2] + red_lds[3];
}

__global__ void k_final(const float* __restrict__ partials, float* __restrict__ out) {
    __shared__ float sred[4];
    float x = partials[threadIdx.x] + partials[threadIdx.x + 256];
    #pragma unroll
    for (int off = 32; off > 0; off >>= 1)
        x += __shfl_xor(x, off);
    if ((threadIdx.x & 63) == 0) sred[threadIdx.x >> 6] = x;
    __syncthreads();
    if (threadIdx.x == 0)
        out[0] = (sred[0] + sred[1] + sred[2] + sred[3]) * INV_M_;
}

extern "C" void kernel_launch(void* const* d_in, const int* in_sizes, int n_in,
                              void* d_out, int out_size, void* d_ws, size_t ws_size,
                              hipStream_t stream) {
    const float* h           = (const float*)d_in[0];
    const float* age         = (const float*)d_in[1];
    const float* targets_age = (const float*)d_in[2];
    const int*   targets     = (const int*)d_in[3];
    const float* W1          = (const float*)d_in[4];
    const float* W2          = (const float*)d_in[5];
    const int*   task_tokens = (const int*)d_in[6];
    const float* time_bins   = (const float*)d_in[7];
    float* out = (float*)d_out;

    char* ws = (char*)d_ws;
    int*   tmap     = (int*)(ws + 0);
    int*   mt       = (int*)(ws + 8192);
    int*   firstocc = (int*)(ws + 40960);
    float* tte      = (float*)(ws + 73728);
    float* partials = (float*)(ws + 2170880);

    hipLaunchKernelGGL(k_tmap, dim3(1), dim3(256), 0, stream, task_tokens, tmap);
    hipLaunchKernelGGL(k_mt, dim3(NROWS_ / 256), dim3(256), 0, stream, targets, tmap, mt);
    hipLaunchKernelGGL(k_firstocc, dim3(B_ * NC_), dim3(64), 0, stream, mt, firstocc);
    hipLaunchKernelGGL(k_tte, dim3(B_ * NC_), dim3(64), 0, stream, mt, firstocc, age, targets_age, tte);
    hipLaunchKernelGGL(k_main, dim3(GRID_MAIN_), dim3(256), 0, stream,
                       h, age, targets_age, W1, W2, time_bins, tte, partials);
    hipLaunchKernelGGL(k_final, dim3(1), dim3(256), 0, stream, partials, out);
}

// Round 2
// 49.009 us; speedup vs baseline: 2.2693x; 2.2693x over previous
//
#include <hip/hip_runtime.h>
#include <hip/hip_bf16.h>

#define B_      4
#define L_      2048
#define NE_     768
#define NOUT_   256     // N_BINS * N_HIDDEN
#define NH_     32
#define NB_     8
#define V_      64
#define VOCAB_  1270
#define NC_     32          // chunks per batch row
#define CS_     64          // L_/NC_
#define BM_     32
#define BK_     32
#define NROWS_  8192
#define GRID_MAIN_ (NROWS_ / BM_)   // 256
#define INV_M_  (1.0f / 4194304.0f) // 1/(B*L*NB*V)

typedef float f32x4 __attribute__((ext_vector_type(4)));
typedef short s16x8 __attribute__((ext_vector_type(8)));

__device__ __forceinline__ short f2bf(float x) {
    union { float f; unsigned u; } c; c.f = x;
    unsigned u = c.u;
    return (short)((u + 0x7fffu + ((u >> 16) & 1u)) >> 16);   // RNE
}

// ---------------- workspace layout (bytes) ----------------
// [0      , 5120   ) tmap      int[1280]
// [8192   , 40960  ) mt        int[B*L]
// [40960  , 73728  ) firstocc  int[B*NC*V]
// [73728  , 2170880) tte       float[B*L*V]
// [2170880, 2564096) W1t       bf16[256][768]   (W1 transposed)
// [2564096, 2568192) W2t       bf16[64][32]     (W2 transposed)
// [2568192, 2569216) partials  float[256]

__global__ void k_tmap(const int* __restrict__ task_tokens, const float* __restrict__ W2,
                       int* __restrict__ tmap, short* __restrict__ W2t) {
    for (int t = threadIdx.x; t < VOCAB_; t += 256) tmap[t] = 0;
    __syncthreads();
    if (threadIdx.x < V_) tmap[task_tokens[threadIdx.x]] = threadIdx.x + 1;
    // W2t[col][j] = bf16(W2[j][col])
    for (int i = threadIdx.x; i < V_ * NH_; i += 256) {
        int col = i >> 5, j = i & 31;
        W2t[col * NH_ + j] = f2bf(W2[j * V_ + col]);
    }
}

__global__ void k_mt(const int* __restrict__ targets, const int* __restrict__ tmap,
                     int* __restrict__ mt) {
    int idx = blockIdx.x * blockDim.x + threadIdx.x;
    if (idx < B_ * L_) mt[idx] = tmap[targets[idx]] - 1;   // -1 = not a task token
}

// W1t[c][k] = bf16(W1[k][c]); block = output row c, coalesced bf16 writes
__global__ void k_w1t(const float* __restrict__ W1, short* __restrict__ W1t) {
    int c = blockIdx.x;
    #pragma unroll
    for (int q = 0; q < 3; ++q) {
        int k = q * 256 + threadIdx.x;
        W1t[c * NE_ + k] = f2bf(W1[k * NOUT_ + c]);
    }
}

// per-chunk first occurrence of class v (lane = v)
__global__ void k_firstocc(const int* __restrict__ mt, int* __restrict__ firstocc) {
    __shared__ int s[CS_];
    int b = blockIdx.x / NC_, c = blockIdx.x % NC_;
    int v = threadIdx.x;
    s[v] = mt[b * L_ + c * CS_ + v];
    __syncthreads();
    int first = 0x7FFFFFFF;
    for (int j = CS_ - 1; j >= 0; --j)
        if (s[j] == v) first = c * CS_ + j;
    firstocc[(b * NC_ + c) * V_ + v] = first;
}

// suffix-min across later chunks + backward scan within chunk; emit tte directly.
// tte[b,i,v] = targets_age[b, tok] - age[b,i] if event exists, else -1.0f sentinel.
__global__ void k_tte(const int* __restrict__ mt, const int* __restrict__ firstocc,
                      const float* __restrict__ age, const float* __restrict__ targets_age,
                      float* __restrict__ tte) {
    __shared__ int s[CS_];
    __shared__ float sage[CS_];
    int b = blockIdx.x / NC_, c = blockIdx.x % NC_;
    int v = threadIdx.x;
    s[v] = mt[b * L_ + c * CS_ + v];
    sage[v] = age[b * L_ + c * CS_ + v];
    __syncthreads();
    int cur = 0x7FFFFFFF;
    for (int cc = c + 1; cc < NC_; ++cc)
        cur = min(cur, firstocc[(b * NC_ + cc) * V_ + v]);
    for (int j = CS_ - 1; j >= 0; --j) {
        int i = c * CS_ + j;
        if (s[j] == v) cur = i;               // event at i itself counts (k >= i)
        float val = -1.0f;
        if (cur != 0x7FFFFFFF) val = targets_age[b * L_ + cur] - sage[j];
        tte[(b * L_ + i) * V_ + v] = val;
    }
}

// main: bf16 MFMA GEMM1 (32 rows x 256 cols, K=768) + MFMA GEMM2 head, fused
__global__ void __launch_bounds__(512)
k_main(const float* __restrict__ h, const float* __restrict__ age,
       const float* __restrict__ targets_age,
       const short* __restrict__ W1t, const short* __restrict__ W2t,
       const float* __restrict__ time_bins,
       const float* __restrict__ tte, float* __restrict__ partials) {
    // padded rows: 40 shorts = 80 B stride -> 2 lanes/bank on b128 frag reads (free)
    __shared__ __align__(16) short sA[BM_][40];        // h tile, bf16
    __shared__ __align__(16) short sB[256][40];        // W1t tile (col-major rows)
    __shared__ __align__(16) short sH[NB_][BM_][40];   // hh, bf16, per bin
    __shared__ __align__(16) short sW2[V_][40];        // W2t staged
    __shared__ float sred[8];

    const int tid = threadIdx.x;
    const int w   = tid >> 6;        // wave 0..7
    const int l   = tid & 63;
    const int l15 = l & 15;
    const int l4  = l >> 4;
    const int r0  = blockIdx.x * BM_;

    // stage W2t -> sW2 once (read only after the K loop's barriers)
    if (tid < 256) {
        int col = tid >> 2, ch = tid & 3;
        *(s16x8*)&sW2[col][ch * 8] = *(const s16x8*)&W2t[col * NH_ + ch * 8];
    }

    // ---- GEMM1 staging indices ----
    const int arow = tid >> 4;               // 0..31
    const int akc  = tid & 15;               // float2 chunk -> k = akc*2
    const int brow = tid >> 2;               // 0..127 (+128 on 2nd slab)
    const int bch  = tid & 3;                // 8-elem chunk

    const float* hA    = &h[(r0 + arow) * NE_ + akc * 2];
    const short* bSrc0 = &W1t[brow * NE_ + bch * 8];
    const short* bSrc1 = &W1t[(brow + 128) * NE_ + bch * 8];

    float2 aReg = *(const float2*)hA;
    s16x8  bReg0 = *(const s16x8*)bSrc0;
    s16x8  bReg1 = *(const s16x8*)bSrc1;

    f32x4 acc[2][2] = {};

    for (int t = 0; t < NE_ / BK_; ++t) {
        __syncthreads();                      // prev iter's frag reads done
        sA[arow][akc * 2]     = f2bf(aReg.x);
        sA[arow][akc * 2 + 1] = f2bf(aReg.y);
        *(s16x8*)&sB[brow][bch * 8]       = bReg0;
        *(s16x8*)&sB[brow + 128][bch * 8] = bReg1;
        int kn = (t + 1) * BK_;
        if (kn < NE_) {                       // prefetch next tile (overlaps MFMA)
            aReg  = *(const float2*)(hA + kn);
            bReg0 = *(const s16x8*)(bSrc0 + kn);
            bReg1 = *(const s16x8*)(bSrc1 + kn);
        }
        __syncthreads();
        // fragments: A row = lane&15, k-chunk = lane>>4 (m89-verified layout)
        s16x8 af0 = *(const s16x8*)&sA[l15][l4 * 8];
        s16x8 af1 = *(const s16x8*)&sA[16 + l15][l4 * 8];
        s16x8 bf0 = *(const s16x8*)&sB[w * 32 + l15][l4 * 8];
        s16x8 bf1 = *(const s16x8*)&sB[w * 32 + 16 + l15][l4 * 8];
        acc[0][0] = __builtin_amdgcn_mfma_f32_16x16x32_bf16(af0, bf0, acc[0][0], 0, 0, 0);
        acc[0][1] = __builtin_amdgcn_mfma_f32_16x16x32_bf16(af0, bf1, acc[0][1], 0, 0, 0);
        acc[1][0] = __builtin_amdgcn_mfma_f32_16x16x32_bf16(af1, bf0, acc[1][0], 0, 0, 0);
        acc[1][1] = __builtin_amdgcn_mfma_f32_16x16x32_bf16(af1, bf1, acc[1][1], 0, 0, 0);
    }

    // ---- write hh to sH as bf16 in A-frag-ready layout ----
    // wave w owns cols [w*32, w*32+32) == bin n = w, jj = col&31
    // C layout: col = lane&15 (+16*cfg), row = (lane>>4)*4 + jr   (m89)
    #pragma unroll
    for (int rf = 0; rf < 2; ++rf)
        #pragma unroll
        for (int cfg = 0; cfg < 2; ++cfg) {
            int jj = cfg * 16 + l15;
            #pragma unroll
            for (int jr = 0; jr < 4; ++jr)
                sH[w][rf * 16 + l4 * 4 + jr][jj] = f2bf(acc[rf][cfg][jr]);
        }
    __syncthreads();

    // ---- GEMM2 + epilogue: wave owns (rf = w&1, cf = w>>1), all 8 bins ----
    const int rf = w & 1;
    const int cf = w >> 1;
    const int v  = cf * 16 + l15;
    s16x8 b2 = *(const s16x8*)&sW2[v][l4 * 8];   // B2[k=j][col=v]

    float tb[NB_ + 1];
    #pragma unroll
    for (int n = 0; n <= NB_; ++n) tb[n] = time_bins[n];

    float tva[4], lcv[4];
    #pragma unroll
    for (int jr = 0; jr < 4; ++jr) {
        int r = r0 + rf * 16 + l4 * 4 + jr;
        int b = r >> 11;
        tva[jr] = tte[r * V_ + v];
        lcv[jr] = targets_age[b * L_ + (L_ - 1)] - age[r];
    }

    float part = 0.0f;
    const f32x4 zero = {};
    #pragma unroll
    for (int n = 0; n < NB_; ++n) {
        s16x8 a2 = *(const s16x8*)&sH[n][rf * 16 + l15][l4 * 8];
        f32x4 c2 = __builtin_amdgcn_mfma_f32_16x16x32_bf16(a2, b2, zero, 0, 0, 0);
        float sn = tb[n], en = tb[n + 1], wn = en - sn;
        #pragma unroll
        for (int jr = 0; jr < 4; ++jr) {
            float ll = c2[jr];
            float ex = __expf(ll);
            float cn = fminf(fmaxf(lcv[jr], 0.0f), wn);
            float tv = tva[jr];
            bool occ = (tv > sn) && (tv <= en);
            part += cn * ex + (occ ? ex * (tv - cn) - ll : 0.0f);
        }
    }

    #pragma unroll
    for (int off = 32; off > 0; off >>= 1) part += __shfl_xor(part, off);
    if (l == 0) sred[w] = part;
    __syncthreads();
    if (tid == 0) {
        float s = 0.0f;
        #pragma unroll
        for (int i = 0; i < 8; ++i) s += sred[i];
        partials[blockIdx.x] = s;
    }
}

__global__ void k_final(const float* __restrict__ partials, float* __restrict__ out) {
    __shared__ float sred[4];
    float x = partials[threadIdx.x];
    #pragma unroll
    for (int off = 32; off > 0; off >>= 1) x += __shfl_xor(x, off);
    if ((threadIdx.x & 63) == 0) sred[threadIdx.x >> 6] = x;
    __syncthreads();
    if (threadIdx.x == 0)
        out[0] = (sred[0] + sred[1] + sred[2] + sred[3]) * INV_M_;
}

extern "C" void kernel_launch(void* const* d_in, const int* in_sizes, int n_in,
                              void* d_out, int out_size, void* d_ws, size_t ws_size,
                              hipStream_t stream) {
    const float* h           = (const float*)d_in[0];
    const float* age         = (const float*)d_in[1];
    const float* targets_age = (const float*)d_in[2];
    const int*   targets     = (const int*)d_in[3];
    const float* W1          = (const float*)d_in[4];
    const float* W2          = (const float*)d_in[5];
    const int*   task_tokens = (const int*)d_in[6];
    const float* time_bins   = (const float*)d_in[7];
    float* out = (float*)d_out;

    char* ws = (char*)d_ws;
    int*   tmap     = (int*)(ws + 0);
    int*   mt       = (int*)(ws + 8192);
    int*   firstocc = (int*)(ws + 40960);
    float* tte      = (float*)(ws + 73728);
    short* W1t      = (short*)(ws + 2170880);
    short* W2t      = (short*)(ws + 2564096);
    float* partials = (float*)(ws + 2568192);

    hipLaunchKernelGGL(k_tmap, dim3(1), dim3(256), 0, stream, task_tokens, W2, tmap, W2t);
    hipLaunchKernelGGL(k_mt, dim3(NROWS_ / 256), dim3(256), 0, stream, targets, tmap, mt);
    hipLaunchKernelGGL(k_w1t, dim3(NOUT_), dim3(256), 0, stream, W1, W1t);
    hipLaunchKernelGGL(k_firstocc, dim3(B_ * NC_), dim3(64), 0, stream, mt, firstocc);
    hipLaunchKernelGGL(k_tte, dim3(B_ * NC_), dim3(64), 0, stream, mt, firstocc, age, targets_age, tte);
    hipLaunchKernelGGL(k_main, dim3(GRID_MAIN_), dim3(512), 0, stream,
                       h, age, targets_age, W1t, W2t, time_bins, tte, partials);
    hipLaunchKernelGGL(k_final, dim3(1), dim3(256), 0, stream, partials, out);
}

// Round 3
// 38.338 us; speedup vs baseline: 2.9009x; 1.2783x over previous
//
#include <hip/hip_runtime.h>
#include <hip/hip_bf16.h>

#define B_      4
#define L_      2048
#define NE_     768
#define NOUT_   256     // N_BINS * N_HIDDEN
#define NH_     32
#define NB_     8
#define V_      64
#define VOCAB_  1270
#define NC_     32          // chunks per batch row
#define CS_     64          // L_/NC_
#define BM_     32
#define BK_     32
#define NROWS_  8192
#define GRID_MAIN_ (NROWS_ / BM_)   // 256
#define INV_M_  (1.0f / 4194304.0f) // 1/(B*L*NB*V)
#define INF_    0x7FFFFFFF

typedef float f32x4 __attribute__((ext_vector_type(4)));
typedef short s16x8 __attribute__((ext_vector_type(8)));

__device__ __forceinline__ unsigned short f2bf(float x) {
    union { float f; unsigned u; } c; c.f = x;
    unsigned u = c.u;
    return (unsigned short)((u + 0x7fffu + ((u >> 16) & 1u)) >> 16);   // RNE
}

// ---------------- workspace layout (bytes) ----------------
// [0     , 5120  ) tmap      int[1280]
// [8192  , 40960 ) mt        int[B*L]
// [40960 , 73728 ) firstocc  int[B*NC*V]
// [73728 , 466944) W1t       bf16[256][768]
// [466944, 471040) W2t       bf16[64][32]
// [471040, 472064) partials  float[256]

// ---- kernel A: block 0 -> tmap + W2t; blocks 1..48 -> W1t transpose tiles
__global__ void __launch_bounds__(256)
k_pre(const int* __restrict__ task_tokens, const float* __restrict__ W1,
      const float* __restrict__ W2,
      int* __restrict__ tmap, short* __restrict__ W1t, short* __restrict__ W2t) {
    const int tid = threadIdx.x;
    if (blockIdx.x == 0) {
        for (int t = tid; t < VOCAB_; t += 256) tmap[t] = 0;
        __syncthreads();
        if (tid < V_) tmap[task_tokens[tid]] = tid + 1;
        // W2t[col][j] = bf16(W2[j][col])
        for (int i = tid; i < V_ * NH_; i += 256) {
            int col = i >> 5, j = i & 31;
            W2t[col * NH_ + j] = (short)f2bf(W2[j * V_ + col]);
        }
        return;
    }
    // transpose tile: 64 k-rows x 64 c-cols of W1 -> W1t
    __shared__ float tl[64][67];
    const int tIdx = blockIdx.x - 1;          // 0..47
    const int kt = (tIdx % 12) * 64;
    const int ct = (tIdx / 12) * 64;
    #pragma unroll
    for (int p = 0; p < 4; ++p) {
        int kk = (tid >> 4) + p * 16;
        int cc = (tid & 15) * 4;
        float4 v = *reinterpret_cast<const float4*>(&W1[(kt + kk) * NOUT_ + ct + cc]);
        tl[kk][cc] = v.x; tl[kk][cc + 1] = v.y; tl[kk][cc + 2] = v.z; tl[kk][cc + 3] = v.w;
    }
    __syncthreads();
    #pragma unroll
    for (int p = 0; p < 8; ++p) {
        int oc  = (tid >> 5) + p * 8;
        int ok2 = (tid & 31) * 2;
        unsigned pk = ((unsigned)f2bf(tl[ok2 + 1][oc]) << 16) | f2bf(tl[ok2][oc]);
        *reinterpret_cast<unsigned*>(&W1t[(ct + oc) * NE_ + kt + ok2]) = pk;
    }
}

// ---- kernel B: per chunk -> mt + firstocc (fused)
__global__ void __launch_bounds__(64)
k_occ(const int* __restrict__ targets, const int* __restrict__ tmap,
      int* __restrict__ mt, int* __restrict__ firstocc) {
    __shared__ int smt[CS_];
    const int b = blockIdx.x >> 5, c = blockIdx.x & 31;
    const int v = threadIdx.x;
    int tgt = targets[b * L_ + c * CS_ + v];
    int mval = tmap[tgt] - 1;                 // -1 = not a task token
    mt[b * L_ + c * CS_ + v] = mval;
    smt[v] = mval;
    __syncthreads();
    int first = INF_;
    for (int j = CS_ - 1; j >= 0; --j)
        if (smt[j] == v) first = c * CS_ + j;
    firstocc[(b * NC_ + c) * V_ + v] = first;
}

// ---- kernel C: fused tte + bf16 MFMA GEMM1 + MFMA GEMM2 + loss partial
__global__ void __launch_bounds__(512)
k_main(const float* __restrict__ h, const float* __restrict__ age,
       const float* __restrict__ targets_age,
       const int* __restrict__ mt, const int* __restrict__ firstocc,
       const short* __restrict__ W1t, const short* __restrict__ W2t,
       const float* __restrict__ time_bins, float* __restrict__ partials) {
    __shared__ __align__(16) short sA[2][BM_][40];
    __shared__ __align__(16) short sB[2][256][40];
    __shared__ __align__(16) short sH[NB_][BM_][40];
    __shared__ __align__(16) short sW2[V_][40];
    __shared__ float stte[BM_][66];
    __shared__ int   smt[CS_];
    __shared__ float sage[BM_];
    __shared__ float sred[8];

    const int tid = threadIdx.x;
    const int w   = tid >> 6;
    const int l   = tid & 63;
    const int l15 = l & 15;
    const int l4  = l >> 4;
    const int r0  = blockIdx.x * BM_;
    const int b   = r0 >> 11;
    const int pos0 = r0 & (L_ - 1);
    const int c    = pos0 >> 6;           // chunk
    const int off  = pos0 - c * CS_;      // 0 or 32

    // ---- issue first GEMM prefetch ----
    const int arow = tid >> 4;
    const int akc  = tid & 15;
    const int brow = tid >> 2;
    const int bch  = tid & 3;
    const float* hA  = &h[(r0 + arow) * NE_ + akc * 2];
    const short* bS0 = &W1t[brow * NE_ + bch * 8];
    const short* bS1 = &W1t[(brow + 128) * NE_ + bch * 8];
    float2 aReg = *(const float2*)hA;
    s16x8  bReg0 = *(const s16x8*)bS0;
    s16x8  bReg1 = *(const s16x8*)bS1;

    // ---- stage small stuff ----
    if (tid < CS_)  smt[tid]  = mt[b * L_ + c * CS_ + tid];
    if (tid < BM_)  sage[tid] = age[r0 + tid];
    if (tid < 256) {
        int col = tid >> 2, ch = tid & 3;
        *(s16x8*)&sW2[col][ch * 8] = *(const s16x8*)&W2t[col * NH_ + ch * 8];
    }
    __syncthreads();

    // ---- inline tte: suffix-min over later chunks + backward chunk scan ----
    {
        const int v  = tid & 63;
        const int rg = tid >> 6;              // row group (4 rows)
        int cur = INF_;
        for (int cc = c + 1; cc < NC_; ++cc)
            cur = min(cur, firstocc[(b * NC_ + cc) * V_ + v]);
        int* stteI = (int*)stte;
        const int jmin = off + rg * 4;
        for (int j = CS_ - 1; j >= jmin; --j) {
            if (smt[j] == v) cur = c * CS_ + j;
            int br = j - off;
            if ((br >> 2) == rg) stteI[br * 66 + v] = cur;
        }
        #pragma unroll
        for (int jr = 0; jr < 4; ++jr) {
            int br  = rg * 4 + jr;
            int tok = stteI[br * 66 + v];
            float val = -1.0f;
            if (tok != INF_) val = targets_age[b * L_ + tok] - sage[br];
            stte[br][v] = val;
        }
    }

    // ---- GEMM1: double-buffered K loop ----
    f32x4 acc[2][2] = {};
    // stage buf 0
    {
        unsigned pk = ((unsigned)f2bf(aReg.y) << 16) | f2bf(aReg.x);
        *(unsigned*)&sA[0][arow][akc * 2] = pk;
        *(s16x8*)&sB[0][brow][bch * 8]       = bReg0;
        *(s16x8*)&sB[0][brow + 128][bch * 8] = bReg1;
    }
    __syncthreads();

    for (int t = 0; t < NE_ / BK_; ++t) {
        const int cur = t & 1;
        if (t < NE_ / BK_ - 1) {
            int kn = (t + 1) * BK_;
            aReg  = *(const float2*)(hA + kn);
            bReg0 = *(const s16x8*)(bS0 + kn);
            bReg1 = *(const s16x8*)(bS1 + kn);
        }
        s16x8 af0 = *(const s16x8*)&sA[cur][l15][l4 * 8];
        s16x8 af1 = *(const s16x8*)&sA[cur][16 + l15][l4 * 8];
        s16x8 bf0 = *(const s16x8*)&sB[cur][w * 32 + l15][l4 * 8];
        s16x8 bf1 = *(const s16x8*)&sB[cur][w * 32 + 16 + l15][l4 * 8];
        acc[0][0] = __builtin_amdgcn_mfma_f32_16x16x32_bf16(af0, bf0, acc[0][0], 0, 0, 0);
        acc[0][1] = __builtin_amdgcn_mfma_f32_16x16x32_bf16(af0, bf1, acc[0][1], 0, 0, 0);
        acc[1][0] = __builtin_amdgcn_mfma_f32_16x16x32_bf16(af1, bf0, acc[1][0], 0, 0, 0);
        acc[1][1] = __builtin_amdgcn_mfma_f32_16x16x32_bf16(af1, bf1, acc[1][1], 0, 0, 0);
        if (t < NE_ / BK_ - 1) {
            unsigned pk = ((unsigned)f2bf(aReg.y) << 16) | f2bf(aReg.x);
            *(unsigned*)&sA[cur ^ 1][arow][akc * 2] = pk;
            *(s16x8*)&sB[cur ^ 1][brow][bch * 8]       = bReg0;
            *(s16x8*)&sB[cur ^ 1][brow + 128][bch * 8] = bReg1;
        }
        __syncthreads();
    }

    // ---- hh -> sH bf16, A-frag layout; wave w owns bin n = w ----
    #pragma unroll
    for (int rf = 0; rf < 2; ++rf)
        #pragma unroll
        for (int cfg = 0; cfg < 2; ++cfg) {
            int jj = cfg * 16 + l15;
            #pragma unroll
            for (int jr = 0; jr < 4; ++jr)
                sH[w][rf * 16 + l4 * 4 + jr][jj] = (short)f2bf(acc[rf][cfg][jr]);
        }
    __syncthreads();

    // ---- GEMM2 + loss: wave owns (rf = w&1, cf = w>>1), all 8 bins ----
    const int rf = w & 1;
    const int cf = w >> 1;
    const int v  = cf * 16 + l15;
    s16x8 b2 = *(const s16x8*)&sW2[v][l4 * 8];

    float tb[NB_ + 1];
    #pragma unroll
    for (int n = 0; n <= NB_; ++n) tb[n] = time_bins[n];

    float tva[4], lcv[4];
    const float lastTA = targets_age[b * L_ + (L_ - 1)];
    #pragma unroll
    for (int jr = 0; jr < 4; ++jr) {
        int br = rf * 16 + l4 * 4 + jr;
        tva[jr] = stte[br][v];
        lcv[jr] = lastTA - sage[br];
    }

    float part = 0.0f;
    const f32x4 zero = {};
    #pragma unroll
    for (int n = 0; n < NB_; ++n) {
        s16x8 a2 = *(const s16x8*)&sH[n][rf * 16 + l15][l4 * 8];
        f32x4 c2 = __builtin_amdgcn_mfma_f32_16x16x32_bf16(a2, b2, zero, 0, 0, 0);
        float sn = tb[n], en = tb[n + 1], wn = en - sn;
        #pragma unroll
        for (int jr = 0; jr < 4; ++jr) {
            float ll = c2[jr];
            float ex = __expf(ll);
            float cn = fminf(fmaxf(lcv[jr], 0.0f), wn);
            float tv = tva[jr];
            bool occ = (tv > sn) && (tv <= en);
            part += cn * ex + (occ ? ex * (tv - cn) - ll : 0.0f);
        }
    }

    #pragma unroll
    for (int offs = 32; offs > 0; offs >>= 1) part += __shfl_xor(part, offs);
    if (l == 0) sred[w] = part;
    __syncthreads();
    if (tid == 0) {
        float s = 0.0f;
        #pragma unroll
        for (int i = 0; i < 8; ++i) s += sred[i];
        partials[blockIdx.x] = s;
    }
}

__global__ void k_final(const float* __restrict__ partials, float* __restrict__ out) {
    __shared__ float sred[4];
    float x = partials[threadIdx.x];
    #pragma unroll
    for (int off = 32; off > 0; off >>= 1) x += __shfl_xor(x, off);
    if ((threadIdx.x & 63) == 0) sred[threadIdx.x >> 6] = x;
    __syncthreads();
    if (threadIdx.x == 0)
        out[0] = (sred[0] + sred[1] + sred[2] + sred[3]) * INV_M_;
}

extern "C" void kernel_launch(void* const* d_in, const int* in_sizes, int n_in,
                              void* d_out, int out_size, void* d_ws, size_t ws_size,
                              hipStream_t stream) {
    const float* h           = (const float*)d_in[0];
    const float* age         = (const float*)d_in[1];
    const float* targets_age = (const float*)d_in[2];
    const int*   targets     = (const int*)d_in[3];
    const float* W1          = (const float*)d_in[4];
    const float* W2          = (const float*)d_in[5];
    const int*   task_tokens = (const int*)d_in[6];
    const float* time_bins   = (const float*)d_in[7];
    float* out = (float*)d_out;

    char* ws = (char*)d_ws;
    int*   tmap     = (int*)(ws + 0);
    int*   mt       = (int*)(ws + 8192);
    int*   firstocc = (int*)(ws + 40960);
    short* W1t      = (short*)(ws + 73728);
    short* W2t      = (short*)(ws + 466944);
    float* partials = (float*)(ws + 471040);

    hipLaunchKernelGGL(k_pre, dim3(49), dim3(256), 0, stream,
                       task_tokens, W1, W2, tmap, W1t, W2t);
    hipLaunchKernelGGL(k_occ, dim3(B_ * NC_), dim3(64), 0, stream,
                       targets, tmap, mt, firstocc);
    hipLaunchKernelGGL(k_main, dim3(GRID_MAIN_), dim3(512), 0, stream,
                       h, age, targets_age, mt, firstocc, W1t, W2t, time_bins, partials);
    hipLaunchKernelGGL(k_final, dim3(1), dim3(256), 0, stream, partials, out);
}

// Round 4
// 37.462 us; speedup vs baseline: 2.9687x; 1.0234x over previous
//
#include <hip/hip_runtime.h>
#include <hip/hip_bf16.h>

#define B_      4
#define L_      2048
#define NE_     768
#define NOUT_   256     // N_BINS * N_HIDDEN
#define NH_     32
#define NB_     8
#define V_      64
#define VOCAB_  1270
#define NC_     32          // chunks per batch row
#define CS_     64          // L_/NC_
#define BM_     32
#define BK_     32
#define NROWS_  8192
#define GRID_MAIN_ 256
#define INV_M_  (1.0f / 4194304.0f) // 1/(B*L*NB*V)
#define INF_    0x7FFFFFFF

typedef float f32x4 __attribute__((ext_vector_type(4)));
typedef short s16x8 __attribute__((ext_vector_type(8)));

__device__ __forceinline__ unsigned short f2bf(float x) {
    union { float f; unsigned u; } c; c.f = x;
    unsigned u = c.u;
    return (unsigned short)((u + 0x7fffu + ((u >> 16) & 1u)) >> 16);   // RNE
}

// ---------------- workspace layout (bytes) ----------------
// [0     , 32768 ) mt        int[B*L]
// [32768 , 65536 ) firstocc  int[B*NC*V]
// [65536 , 458752) W1t       bf16[256][768]
// [458752, 462848) W2t       bf16[64][32]
// [462848, 463872) partials  float[256]
// [463872, 463876) cnt       unsigned

// ---- kernel 1: blocks 0..47 W1t transpose; block 48 W2t + cnt reset;
//                blocks 49..80 mt + firstocc (4 chunks per block)
__global__ void __launch_bounds__(256)
k_prep(const int* __restrict__ task_tokens, const float* __restrict__ W1,
       const float* __restrict__ W2, const int* __restrict__ targets,
       short* __restrict__ W1t, short* __restrict__ W2t,
       int* __restrict__ mt, int* __restrict__ firstocc, unsigned* __restrict__ cnt) {
    __shared__ float tl[64][67];
    __shared__ int   stask[V_];
    __shared__ int   smt[4][CS_];
    const int tid = threadIdx.x;

    if (blockIdx.x < 48) {
        // transpose tile: 64 k-rows x 64 c-cols of W1 -> W1t (bf16)
        const int tIdx = blockIdx.x;
        const int kt = (tIdx % 12) * 64;
        const int ct = (tIdx / 12) * 64;
        #pragma unroll
        for (int p = 0; p < 4; ++p) {
            int kk = (tid >> 4) + p * 16;
            int cc = (tid & 15) * 4;
            float4 v = *reinterpret_cast<const float4*>(&W1[(kt + kk) * NOUT_ + ct + cc]);
            tl[kk][cc] = v.x; tl[kk][cc + 1] = v.y; tl[kk][cc + 2] = v.z; tl[kk][cc + 3] = v.w;
        }
        __syncthreads();
        #pragma unroll
        for (int p = 0; p < 8; ++p) {
            int oc  = (tid >> 5) + p * 8;
            int ok2 = (tid & 31) * 2;
            unsigned pk = ((unsigned)f2bf(tl[ok2 + 1][oc]) << 16) | f2bf(tl[ok2][oc]);
            *reinterpret_cast<unsigned*>(&W1t[(ct + oc) * NE_ + kt + ok2]) = pk;
        }
        return;
    }
    if (blockIdx.x == 48) {
        // W2t[col][j] = bf16(W2[j][col]); reset completion counter
        if (tid == 0) cnt[0] = 0u;
        #pragma unroll
        for (int q = 0; q < 8; ++q) {
            int i = tid + q * 256;
            int col = i >> 5, j = i & 31;
            W2t[col * NH_ + j] = (short)f2bf(W2[j * V_ + col]);
        }
        return;
    }
    // ---- occ blocks: 4 chunks each ----
    if (tid < V_) stask[tid] = task_tokens[tid];
    __syncthreads();
    const int gi = tid >> 6;            // chunk group 0..3 (one wave each)
    const int v  = tid & 63;
    const int g  = (blockIdx.x - 49) * 4 + gi;     // global chunk 0..127
    const int b  = g >> 5, c = g & 31;
    int t = targets[b * L_ + c * CS_ + v];
    int mval = -1;
    #pragma unroll
    for (int j = 0; j < V_; ++j)
        mval = (stask[j] == t) ? j : mval;        // ascending: last match wins
    mt[b * L_ + c * CS_ + v] = mval;
    smt[gi][v] = mval;                            // wave-local: no barrier needed
    int first = INF_;
    for (int j = CS_ - 1; j >= 0; --j)
        if (smt[gi][j] == v) first = c * CS_ + j;
    firstocc[(b * NC_ + c) * V_ + v] = first;
}

// ---- kernel 2: fused tte + bf16 MFMA GEMM1 + MFMA GEMM2 + loss + final reduce
__global__ void __launch_bounds__(512)
k_main(const float* __restrict__ h, const float* __restrict__ age,
       const float* __restrict__ targets_age,
       const int* __restrict__ mt, const int* __restrict__ firstocc,
       const short* __restrict__ W1t, const short* __restrict__ W2t,
       const float* __restrict__ time_bins, float* __restrict__ partials,
       unsigned* __restrict__ cnt, float* __restrict__ out) {
    __shared__ __align__(16) short sA[2][BM_][40];
    __shared__ __align__(16) short sB[2][256][40];
    __shared__ __align__(16) short sH[NB_][BM_][40];
    __shared__ __align__(16) short sW2[V_][40];
    __shared__ float stte[BM_][66];
    __shared__ int   sminI[8][V_];
    __shared__ int   smt[CS_];
    __shared__ float sage[BM_];
    __shared__ float sred[8];
    __shared__ float s2[4];
    __shared__ int   sLast;

    const int tid = threadIdx.x;
    const int w   = tid >> 6;
    const int l   = tid & 63;
    const int l15 = l & 15;
    const int l4  = l >> 4;
    const int r0  = blockIdx.x * BM_;
    const int b   = r0 >> 11;
    const int pos0 = r0 & (L_ - 1);
    const int c    = pos0 >> 6;           // chunk
    const int off  = pos0 - c * CS_;      // 0 or 32

    // ---- issue first GEMM prefetch ----
    const int arow = tid >> 4;
    const int akc  = tid & 15;
    const int brow = tid >> 2;
    const int bch  = tid & 3;
    const float* hA  = &h[(r0 + arow) * NE_ + akc * 2];
    const short* bS0 = &W1t[brow * NE_ + bch * 8];
    const short* bS1 = &W1t[(brow + 128) * NE_ + bch * 8];
    float2 aReg = *(const float2*)hA;
    s16x8  bReg0 = *(const s16x8*)bS0;
    s16x8  bReg1 = *(const s16x8*)bS1;

    // ---- stage small stuff ----
    if (tid < CS_)  smt[tid]  = mt[b * L_ + c * CS_ + tid];
    if (tid < BM_)  sage[tid] = age[r0 + tid];
    if (tid < 256) {
        int col = tid >> 2, ch = tid & 3;
        *(s16x8*)&sW2[col][ch * 8] = *(const s16x8*)&W2t[col * NH_ + ch * 8];
    }

    // ---- wave-parallel suffix-min over later chunks (<=4 loads, unrolled) ----
    {
        int cur = INF_;
        #pragma unroll
        for (int k = 0; k < 4; ++k) {
            int cc = c + 1 + w + k * 8;
            if (cc < NC_) cur = min(cur, firstocc[(b * NC_ + cc) * V_ + l]);
        }
        sminI[w][l] = cur;
    }
    __syncthreads();

    // ---- inline tte: combine suffix-min + backward chunk scan ----
    {
        const int v  = l;
        const int rg = w;                     // row group (4 rows)
        int cur = INF_;
        #pragma unroll
        for (int ww = 0; ww < 8; ++ww) cur = min(cur, sminI[ww][v]);
        int* stteI = (int*)stte;
        const int jmin = off + rg * 4;
        for (int j = CS_ - 1; j >= jmin; --j) {
            if (smt[j] == v) cur = c * CS_ + j;
            int br = j - off;
            if ((br >> 2) == rg) stteI[br * 66 + v] = cur;
        }
        #pragma unroll
        for (int jr = 0; jr < 4; ++jr) {
            int br  = rg * 4 + jr;
            int tok = stteI[br * 66 + v];
            float val = -1.0f;
            if (tok != INF_) val = targets_age[b * L_ + tok] - sage[br];
            stte[br][v] = val;
        }
    }

    // ---- GEMM1: double-buffered K loop ----
    f32x4 acc[2][2] = {};
    {
        unsigned pk = ((unsigned)f2bf(aReg.y) << 16) | f2bf(aReg.x);
        *(unsigned*)&sA[0][arow][akc * 2] = pk;
        *(s16x8*)&sB[0][brow][bch * 8]       = bReg0;
        *(s16x8*)&sB[0][brow + 128][bch * 8] = bReg1;
    }
    __syncthreads();

    for (int t = 0; t < NE_ / BK_; ++t) {
        const int cur = t & 1;
        if (t < NE_ / BK_ - 1) {
            int kn = (t + 1) * BK_;
            aReg  = *(const float2*)(hA + kn);
            bReg0 = *(const s16x8*)(bS0 + kn);
            bReg1 = *(const s16x8*)(bS1 + kn);
        }
        s16x8 af0 = *(const s16x8*)&sA[cur][l15][l4 * 8];
        s16x8 af1 = *(const s16x8*)&sA[cur][16 + l15][l4 * 8];
        s16x8 bf0 = *(const s16x8*)&sB[cur][w * 32 + l15][l4 * 8];
        s16x8 bf1 = *(const s16x8*)&sB[cur][w * 32 + 16 + l15][l4 * 8];
        acc[0][0] = __builtin_amdgcn_mfma_f32_16x16x32_bf16(af0, bf0, acc[0][0], 0, 0, 0);
        acc[0][1] = __builtin_amdgcn_mfma_f32_16x16x32_bf16(af0, bf1, acc[0][1], 0, 0, 0);
        acc[1][0] = __builtin_amdgcn_mfma_f32_16x16x32_bf16(af1, bf0, acc[1][0], 0, 0, 0);
        acc[1][1] = __builtin_amdgcn_mfma_f32_16x16x32_bf16(af1, bf1, acc[1][1], 0, 0, 0);
        if (t < NE_ / BK_ - 1) {
            unsigned pk = ((unsigned)f2bf(aReg.y) << 16) | f2bf(aReg.x);
            *(unsigned*)&sA[cur ^ 1][arow][akc * 2] = pk;
            *(s16x8*)&sB[cur ^ 1][brow][bch * 8]       = bReg0;
            *(s16x8*)&sB[cur ^ 1][brow + 128][bch * 8] = bReg1;
        }
        __syncthreads();
    }

    // ---- hh -> sH bf16, A-frag layout; wave w owns bin n = w ----
    #pragma unroll
    for (int rf = 0; rf < 2; ++rf)
        #pragma unroll
        for (int cfg = 0; cfg < 2; ++cfg) {
            int jj = cfg * 16 + l15;
            #pragma unroll
            for (int jr = 0; jr < 4; ++jr)
                sH[w][rf * 16 + l4 * 4 + jr][jj] = (short)f2bf(acc[rf][cfg][jr]);
        }
    __syncthreads();

    // ---- GEMM2 + loss: wave owns (rf = w&1, cf = w>>1), all 8 bins ----
    const int rf = w & 1;
    const int cf = w >> 1;
    const int v  = cf * 16 + l15;
    s16x8 b2 = *(const s16x8*)&sW2[v][l4 * 8];

    float tb[NB_ + 1];
    #pragma unroll
    for (int n = 0; n <= NB_; ++n) tb[n] = time_bins[n];

    float tva[4], lcv[4];
    const float lastTA = targets_age[b * L_ + (L_ - 1)];
    #pragma unroll
    for (int jr = 0; jr < 4; ++jr) {
        int br = rf * 16 + l4 * 4 + jr;
        tva[jr] = stte[br][v];
        lcv[jr] = lastTA - sage[br];
    }

    float part = 0.0f;
    const f32x4 zero = {};
    #pragma unroll
    for (int n = 0; n < NB_; ++n) {
        s16x8 a2 = *(const s16x8*)&sH[n][rf * 16 + l15][l4 * 8];
        f32x4 c2 = __builtin_amdgcn_mfma_f32_16x16x32_bf16(a2, b2, zero, 0, 0, 0);
        float sn = tb[n], en = tb[n + 1], wn = en - sn;
        #pragma unroll
        for (int jr = 0; jr < 4; ++jr) {
            float ll = c2[jr];
            float ex = __expf(ll);
            float tv = tva[jr];
            bool occ = (tv > sn) && (tv <= en);
            float cn = fminf(fmaxf(lcv[jr], 0.0f), wn);
            // occ: ex*tv - ll   (cn terms cancel exactly); else: ex*cn
            part += ex * (occ ? tv : cn) - (occ ? ll : 0.0f);
        }
    }

    #pragma unroll
    for (int offs = 32; offs > 0; offs >>= 1) part += __shfl_xor(part, offs);
    if (l == 0) sred[w] = part;
    __syncthreads();
    if (tid == 0) {
        float s = 0.0f;
        #pragma unroll
        for (int i = 0; i < 8; ++i) s += sred[i];
        __hip_atomic_store(&partials[blockIdx.x], s, __ATOMIC_RELEASE, __HIP_MEMORY_SCOPE_AGENT);
        unsigned old = __hip_atomic_fetch_add(cnt, 1u, __ATOMIC_ACQ_REL, __HIP_MEMORY_SCOPE_AGENT);
        sLast = (old == GRID_MAIN_ - 1u);
    }
    __syncthreads();
    if (sLast) {
        float x = 0.0f;
        if (tid < 256)
            x = __hip_atomic_load(&partials[tid], __ATOMIC_RELAXED, __HIP_MEMORY_SCOPE_AGENT);
        #pragma unroll
        for (int o = 32; o > 0; o >>= 1) x += __shfl_xor(x, o);
        if (tid < 256 && (tid & 63) == 0) s2[tid >> 6] = x;
        __syncthreads();
        if (tid == 0) out[0] = (s2[0] + s2[1] + s2[2] + s2[3]) * INV_M_;
    }
}

extern "C" void kernel_launch(void* const* d_in, const int* in_sizes, int n_in,
                              void* d_out, int out_size, void* d_ws, size_t ws_size,
                              hipStream_t stream) {
    const float* h           = (const float*)d_in[0];
    const float* age         = (const float*)d_in[1];
    const float* targets_age = (const float*)d_in[2];
    const int*   targets     = (const int*)d_in[3];
    const float* W1          = (const float*)d_in[4];
    const float* W2          = (const float*)d_in[5];
    const int*   task_tokens = (const int*)d_in[6];
    const float* time_bins   = (const float*)d_in[7];
    float* out = (float*)d_out;

    char* ws = (char*)d_ws;
    int*      mt       = (int*)(ws + 0);
    int*      firstocc = (int*)(ws + 32768);
    short*    W1t      = (short*)(ws + 65536);
    short*    W2t      = (short*)(ws + 458752);
    float*    partials = (float*)(ws + 462848);
    unsigned* cnt      = (unsigned*)(ws + 463872);

    hipLaunchKernelGGL(k_prep, dim3(81), dim3(256), 0, stream,
                       task_tokens, W1, W2, targets, W1t, W2t, mt, firstocc, cnt);
    hipLaunchKernelGGL(k_main, dim3(GRID_MAIN_), dim3(512), 0, stream,
                       h, age, targets_age, mt, firstocc, W1t, W2t, time_bins,
                       partials, cnt, out);
}